// Round 1
// baseline (383.946 us; speedup 1.0000x reference)
//
#include <hip/hip_runtime.h>

// SurvModel: x=relu(BN(in@W1+b1)); h=tanh(BN(x@Watt1+batt1)); s=h@Watt2+batt2;
// A=softmax_N(s); top64 by A desc (stable); zs=x[top]*softmax(A[top]);
// zq/zk/zv=zs@W*; zw=softmax(zq@zk^T)@zv; out=relu(zw.flat@Wz+bz)@Wf+bf.
// Strategy: split-fp32 (bf16 hi/lo, 3 MFMAs) for the big GEMM so scores are
// ~1e-6 accurate (top-64 gap ~1.3e-3). Memory-bound: 402MB read ~64us floor.

#define NN   131072
#define DIN  768
#define DH   128
#define DA   32

using f32x4  = __attribute__((ext_vector_type(4))) float;
using bf16x8 = __attribute__((ext_vector_type(8))) __bf16;

// workspace byte offsets
#define WS_S      0            // float[131072] scores
#define WS_PZ     524288       // float[1024] per-block sum(exp(s))
#define WS_HIST   528384       // int[4096]
#define WS_MISC   544768       // [0]=Z f32, [2]=cnt int, [3]=bstar int
#define WS_CIDX   544832       // int[512]
#define WS_CS     546880       // float[512]
#define WS_ORDER  548928       // int[64]
#define WS_W      549184       // float[64]
#define WS_ZQ     549440       // float[2048]
#define WS_ZK     557632       // float[2048]
#define WS_ZV     565824       // float[2048]
#define WS_ZW     574016       // float[2048]
#define WS_O128   582208       // float[128]

__device__ __forceinline__ int s_bin(float s) {
  int b = (int)((s + 6.0f) * (4096.0f / 12.0f));
  return b < 0 ? 0 : (b > 4095 ? 4095 : b);
}

// ---------------- K1: main GEMM + h + scores ----------------
__global__ __launch_bounds__(256, 2) void k_main(
    const float* __restrict__ inp, const float* __restrict__ W1,
    const float* __restrict__ b1, const float* __restrict__ g1, const float* __restrict__ be1,
    const float* __restrict__ Watt1, const float* __restrict__ batt1,
    const float* __restrict__ g2, const float* __restrict__ be2,
    const float* __restrict__ Watt2, const float* __restrict__ batt2,
    char* __restrict__ ws)
{
  // LDS: [0,16K) A-stage | [16K,32K) B-stage ; union with x-tile [0,64K); Watt1 [64K,80K)
  __shared__ __align__(16) char lds[80 * 1024];
  __shared__ float zscr[8];
  float* s_out = (float*)(ws + WS_S);
  float* pz    = (float*)(ws + WS_PZ);
  int*   hist  = (int*)(ws + WS_HIST);

  const int t = threadIdx.x;
  const int l = t & 63;
  const int wid = t >> 6;
  const int wr = wid >> 1, wc = wid & 1;
  const int blockRow = blockIdx.x * 128;
  const float inv = 1.0f / sqrtf(1.0f + 1e-5f);

  char* Astg = lds;
  char* Bstg = lds + 16384;
  float* xt  = (float*)lds;
  float* wat = (float*)(lds + 65536);

  const int srow  = t >> 1;   // staging row (A) / col (B), 0..127
  const int shalf = t & 1;    // k half (16 values)

  f32x4 acc[4][4];
  #pragma unroll
  for (int i = 0; i < 4; ++i)
    #pragma unroll
    for (int j = 0; j < 4; ++j)
      #pragma unroll
      for (int q = 0; q < 4; ++q) acc[i][j][q] = 0.0f;

  for (int i = t; i < DH * DA; i += 256) wat[i] = Watt1[i];

  // prologue loads (kc = 0)
  f32x4 av0, av1, av2, av3;
  float bv[16];
  {
    const float* ap = inp + (size_t)(blockRow + srow) * DIN + shalf * 16;
    av0 = *(const f32x4*)(ap + 0);  av1 = *(const f32x4*)(ap + 4);
    av2 = *(const f32x4*)(ap + 8);  av3 = *(const f32x4*)(ap + 12);
    const float* bp = W1 + (size_t)(shalf * 16) * DH + srow;
    #pragma unroll
    for (int kk2 = 0; kk2 < 16; ++kk2) bv[kk2] = bp[(size_t)kk2 * DH];
  }

  for (int kc = 0; kc < 24; ++kc) {
    // convert staged regs to bf16 hi/lo (split-fp32)
    bf16x8 ah0, ah1, al0, al1, bh0, bh1, bl0, bl1;
    {
      float aval[16];
      #pragma unroll
      for (int q = 0; q < 4; ++q) {
        aval[q] = av0[q]; aval[4+q] = av1[q]; aval[8+q] = av2[q]; aval[12+q] = av3[q];
      }
      #pragma unroll
      for (int j = 0; j < 8; ++j) {
        { float x = aval[j];   __bf16 h = (__bf16)x; ah0[j] = h; al0[j] = (__bf16)(x - (float)h); }
        { float x = aval[8+j]; __bf16 h = (__bf16)x; ah1[j] = h; al1[j] = (__bf16)(x - (float)h); }
        { float x = bv[j];     __bf16 h = (__bf16)x; bh0[j] = h; bl0[j] = (__bf16)(x - (float)h); }
        { float x = bv[8+j];   __bf16 h = (__bf16)x; bh1[j] = h; bl1[j] = (__bf16)(x - (float)h); }
      }
    }
    __builtin_amdgcn_s_barrier();            // all waves done reading stage
    __builtin_amdgcn_sched_barrier(0);
    {
      // layout per row/col: [hi 32*bf16 | lo 32*bf16] = 128B, XOR-swizzled 16B units
      char* Ab = Astg + srow * 128; int sa = (srow & 7) << 4;
      *(bf16x8*)(Ab + ((shalf * 32 + 0)  ^ sa)) = ah0;
      *(bf16x8*)(Ab + ((shalf * 32 + 16) ^ sa)) = ah1;
      *(bf16x8*)(Ab + ((64 + shalf * 32 + 0)  ^ sa)) = al0;
      *(bf16x8*)(Ab + ((64 + shalf * 32 + 16) ^ sa)) = al1;
      char* Bb = Bstg + srow * 128;
      *(bf16x8*)(Bb + ((shalf * 32 + 0)  ^ sa)) = bh0;
      *(bf16x8*)(Bb + ((shalf * 32 + 16) ^ sa)) = bh1;
      *(bf16x8*)(Bb + ((64 + shalf * 32 + 0)  ^ sa)) = bl0;
      *(bf16x8*)(Bb + ((64 + shalf * 32 + 16) ^ sa)) = bl1;
    }
    asm volatile("s_waitcnt lgkmcnt(0)" ::: "memory");
    __builtin_amdgcn_s_barrier();            // stage visible
    __builtin_amdgcn_sched_barrier(0);
    if (kc < 23) {                           // issue next loads; in flight over compute
      const float* ap = inp + (size_t)(blockRow + srow) * DIN + (kc + 1) * 32 + shalf * 16;
      av0 = *(const f32x4*)(ap + 0);  av1 = *(const f32x4*)(ap + 4);
      av2 = *(const f32x4*)(ap + 8);  av3 = *(const f32x4*)(ap + 12);
      const float* bp = W1 + (size_t)((kc + 1) * 32 + shalf * 16) * DH + srow;
      #pragma unroll
      for (int kk2 = 0; kk2 < 16; ++kk2) bv[kk2] = bp[(size_t)kk2 * DH];
    }
    {
      const int kg = l >> 4;
      bf16x8 ahi[4], alo[4];
      #pragma unroll
      for (int mi = 0; mi < 4; ++mi) {
        int row = wr * 64 + mi * 16 + (l & 15);
        const char* rb = Astg + row * 128; int sw = (row & 7) << 4;
        ahi[mi] = *(const bf16x8*)(rb + ((kg * 16) ^ sw));
        alo[mi] = *(const bf16x8*)(rb + ((64 + kg * 16) ^ sw));
      }
      #pragma unroll
      for (int ni = 0; ni < 4; ++ni) {
        int col = wc * 64 + ni * 16 + (l & 15);
        const char* cb = Bstg + col * 128; int sw = (col & 7) << 4;
        bf16x8 bhi = *(const bf16x8*)(cb + ((kg * 16) ^ sw));
        bf16x8 blo = *(const bf16x8*)(cb + ((64 + kg * 16) ^ sw));
        #pragma unroll
        for (int mi = 0; mi < 4; ++mi) {
          acc[mi][ni] = __builtin_amdgcn_mfma_f32_16x16x32_bf16(ahi[mi], bhi, acc[mi][ni], 0, 0, 0);
          acc[mi][ni] = __builtin_amdgcn_mfma_f32_16x16x32_bf16(ahi[mi], blo, acc[mi][ni], 0, 0, 0);
          acc[mi][ni] = __builtin_amdgcn_mfma_f32_16x16x32_bf16(alo[mi], bhi, acc[mi][ni], 0, 0, 0);
        }
      }
    }
  }
  __syncthreads();
  // epilogue: BN + relu -> x tile in LDS (fp32, row-XOR-swizzled)
  #pragma unroll
  for (int ni = 0; ni < 4; ++ni) {
    int col = wc * 64 + ni * 16 + (l & 15);
    float b1c = b1[col], s1c = g1[col] * inv, be1c = be1[col];
    #pragma unroll
    for (int mi = 0; mi < 4; ++mi) {
      int rbase = wr * 64 + mi * 16 + ((l >> 4) << 2);
      #pragma unroll
      for (int q = 0; q < 4; ++q) {
        int row = rbase + q;
        float xv = fmaxf((acc[mi][ni][q] + b1c) * s1c + be1c, 0.0f);
        *(float*)((char*)xt + row * 512 + ((col * 4) ^ ((row & 31) << 4))) = xv;
      }
    }
  }
  __syncthreads();
  // h = tanh(BN(x@Watt1)); s = h@Watt2 + batt2; Z partials; histogram
  {
    const int row = t >> 1, ah = t & 1;
    float hacc[16];
    #pragma unroll
    for (int a = 0; a < 16; ++a) hacc[a] = 0.0f;
    const char* xrow = (const char*)xt + row * 512;
    const int rsw = (row & 31) << 4;
    for (int cb = 0; cb < 128; cb += 4) {
      f32x4 xv = *(const f32x4*)(xrow + ((cb * 4) ^ rsw));
      #pragma unroll
      for (int u = 0; u < 4; ++u) {
        const float* wrow = wat + (cb + u) * 32 + ah * 16;
        f32x4 w0 = *(const f32x4*)(wrow);
        f32x4 w1 = *(const f32x4*)(wrow + 4);
        f32x4 w2 = *(const f32x4*)(wrow + 8);
        f32x4 w3 = *(const f32x4*)(wrow + 12);
        float xs = xv[u];
        #pragma unroll
        for (int q = 0; q < 4; ++q) {
          hacc[q]    += xs * w0[q];
          hacc[4+q]  += xs * w1[q];
          hacc[8+q]  += xs * w2[q];
          hacc[12+q] += xs * w3[q];
        }
      }
    }
    float partial = 0.0f;
    #pragma unroll
    for (int a = 0; a < 16; ++a) {
      int ai = ah * 16 + a;
      float hv = tanhf((hacc[a] + batt1[ai]) * (g2[ai] * inv) + be2[ai]);
      partial += hv * Watt2[ai];
    }
    partial += __shfl_xor(partial, 1, 64);
    float ev = 0.0f;
    if (ah == 0) {
      float sv = partial + batt2[0];
      s_out[blockRow + row] = sv;
      atomicAdd(&hist[s_bin(sv)], 1);
      ev = expf(sv);
    }
    #pragma unroll
    for (int off = 32; off >= 1; off >>= 1) ev += __shfl_xor(ev, off, 64);
    if (l == 0) zscr[wid] = ev;
    __syncthreads();
    if (t == 0) pz[blockIdx.x] = zscr[0] + zscr[1] + zscr[2] + zscr[3];
  }
}

// ---------------- K2: Z reduce + histogram threshold ----------------
__global__ void k_reduce(char* __restrict__ ws) {
  float* pz = (float*)(ws + WS_PZ);
  int* hist = (int*)(ws + WS_HIST);
  float* miscf = (float*)(ws + WS_MISC);
  int* misci = (int*)(ws + WS_MISC);
  const int t = threadIdx.x;
  __shared__ float red[256];
  __shared__ int csum[256];
  float z = 0.0f;
  for (int i = t; i < 1024; i += 256) z += pz[i];
  red[t] = z;
  int c = 0;
  #pragma unroll
  for (int u = 0; u < 16; ++u) c += hist[t * 16 + u];
  csum[t] = c;
  __syncthreads();
  for (int off = 128; off >= 1; off >>= 1) {
    if (t < off) red[t] += red[t + off];
    __syncthreads();
  }
  if (t == 0) {
    miscf[0] = red[0];
    int cum = 0, bstar = 0;
    for (int ch = 255; ch >= 0; --ch) {
      if (cum + csum[ch] >= 64) {
        for (int b = ch * 16 + 15; b >= ch * 16; --b) {
          cum += hist[b];
          if (cum >= 64) { bstar = b; break; }
        }
        break;
      }
      cum += csum[ch];
    }
    misci[3] = bstar;
    misci[2] = 0;
  }
}

// ---------------- K3: gather candidates ----------------
__global__ void k_gather(char* __restrict__ ws) {
  const int i = blockIdx.x * 256 + threadIdx.x;
  float* s_out = (float*)(ws + WS_S);
  int* misci = (int*)(ws + WS_MISC);
  int* cidx = (int*)(ws + WS_CIDX);
  float* cs = (float*)(ws + WS_CS);
  float s = s_out[i];
  if (s_bin(s) >= misci[3]) {
    int pos = atomicAdd(&misci[2], 1);
    if (pos < 512) { cidx[pos] = i; cs[pos] = s; }
  }
}

// ---------------- K4: sort candidates, top-64 order + weights ----------------
__global__ void k_select(char* __restrict__ ws) {
  const int t = threadIdx.x;
  float* s_out = (float*)(ws + WS_S);
  int* misci = (int*)(ws + WS_MISC);
  float* miscf = (float*)(ws + WS_MISC);
  int* cidx = (int*)(ws + WS_CIDX);
  float* cs = (float*)(ws + WS_CS);
  int* order = (int*)(ws + WS_ORDER);
  float* wsel = (float*)(ws + WS_W);
  __shared__ unsigned long long keys[512];
  __shared__ float aLds[64];
  int cnt = misci[2]; if (cnt > 512) cnt = 512;
  for (int i = t; i < 512; i += 256) {
    unsigned long long kkey = 0xFFFFFFFFFFFFFFFFull;
    if (i < cnt) {
      unsigned u = __float_as_uint(cs[i]);
      u = (u & 0x80000000u) ? ~u : (u | 0x80000000u);  // ascending map
      unsigned du = ~u;                                 // descending by s
      kkey = ((unsigned long long)du << 32) | (unsigned)cidx[i];  // tie: idx asc
    }
    keys[i] = kkey;
  }
  __syncthreads();
  for (int k = 2; k <= 512; k <<= 1) {
    for (int j = k >> 1; j > 0; j >>= 1) {
      for (int i = t; i < 512; i += 256) {
        int ixj = i ^ j;
        if (ixj > i) {
          bool up = ((i & k) == 0);
          unsigned long long a = keys[i], b2 = keys[ixj];
          if (up ? (a > b2) : (a < b2)) { keys[i] = b2; keys[ixj] = a; }
        }
      }
      __syncthreads();
    }
  }
  float Z = miscf[0];
  if (t < 64) {
    int idx = (int)(keys[t] & 0xFFFFFFFFull);
    order[t] = idx;
    aLds[t] = expf(s_out[idx]) / Z;   // A values (softmax over N, unnormalized-max form)
  }
  __syncthreads();
  if (t < 64) {
    float m = aLds[0];                // sorted desc -> max
    float e = expf(aLds[t] - m);
    float sum = e;
    #pragma unroll
    for (int off = 32; off >= 1; off >>= 1) sum += __shfl_xor(sum, off, 64);
    wsel[t] = e / sum;
  }
}

// ---------------- K5: recompute x for top-64, zs, zq/zk/zv ----------------
__global__ void k_zs(const float* __restrict__ inp, const float* __restrict__ W1,
                     const float* __restrict__ b1, const float* __restrict__ g1, const float* __restrict__ be1,
                     const float* __restrict__ Wq, const float* __restrict__ Wk, const float* __restrict__ Wv,
                     char* __restrict__ ws)
{
  const int t = threadIdx.x, b = blockIdx.x;
  int* order = (int*)(ws + WS_ORDER);
  float* wsel = (float*)(ws + WS_W);
  float* zq = (float*)(ws + WS_ZQ);
  float* zk = (float*)(ws + WS_ZK);
  float* zv = (float*)(ws + WS_ZV);
  __shared__ float rowS[768];
  __shared__ float zsS[128];
  const float inv = 1.0f / sqrtf(1.0f + 1e-5f);
  int r = order[b];
  float wgt = wsel[b];
  for (int i = t; i < 768; i += 256) rowS[i] = inp[(size_t)r * 768 + i];
  __syncthreads();
  if (t < 128) {
    float d = 0.0f;
    for (int k = 0; k < 768; ++k) d += rowS[k] * W1[(size_t)k * 128 + t];
    float x = fmaxf((d + b1[t]) * (g1[t] * inv) + be1[t], 0.0f);
    zsS[t] = x * wgt;
  }
  __syncthreads();
  if (t < 96) {
    int which = t >> 5, a = t & 31;
    const float* W = (which == 0) ? Wq : ((which == 1) ? Wk : Wv);
    float d = 0.0f;
    for (int c = 0; c < 128; ++c) d += zsS[c] * W[c * 32 + a];
    float* dst = (which == 0) ? zq : ((which == 1) ? zk : zv);
    dst[b * 32 + a] = d;
  }
}

// ---------------- K6a: 64x64 attention ----------------
__global__ void k_attn(char* __restrict__ ws) {
  const int t = threadIdx.x;
  float* zq = (float*)(ws + WS_ZQ);
  float* zk = (float*)(ws + WS_ZK);
  float* zv = (float*)(ws + WS_ZV);
  float* zw = (float*)(ws + WS_ZW);
  __shared__ float q[2048], kk[2048], v[2048], P[4096];
  for (int i = t; i < 2048; i += 256) { q[i] = zq[i]; kk[i] = zk[i]; v[i] = zv[i]; }
  __syncthreads();
  for (int o = t; o < 4096; o += 256) {
    int i = o >> 6, j = o & 63;
    float d = 0.0f;
    for (int a = 0; a < 32; ++a) d += q[i * 32 + a] * kk[j * 32 + a];
    P[o] = d;
  }
  __syncthreads();
  if (t < 64) {
    float m = -1e30f;
    for (int j = 0; j < 64; ++j) m = fmaxf(m, P[t * 64 + j]);
    float sum = 0.0f;
    for (int j = 0; j < 64; ++j) { float e = expf(P[t * 64 + j] - m); P[t * 64 + j] = e; sum += e; }
    float rs = 1.0f / sum;
    for (int j = 0; j < 64; ++j) P[t * 64 + j] *= rs;
  }
  __syncthreads();
  for (int o = t; o < 2048; o += 256) {
    int i = o >> 5, a = o & 31;
    float d = 0.0f;
    for (int j = 0; j < 64; ++j) d += P[i * 64 + j] * v[j * 32 + a];
    zw[o] = d;
  }
}

// ---------------- K6b: zw.flat @ Wz + bz, relu ----------------
__global__ void k_wz(const float* __restrict__ Wz, const float* __restrict__ bz, char* __restrict__ ws) {
  const int t = threadIdx.x, j = blockIdx.x;
  float* zw = (float*)(ws + WS_ZW);
  float* o128 = (float*)(ws + WS_O128);
  __shared__ float red[256];
  float p = 0.0f;
  for (int i2 = t; i2 < 2048; i2 += 256) p += zw[i2] * Wz[(size_t)i2 * 128 + j];
  red[t] = p; __syncthreads();
  for (int off = 128; off >= 1; off >>= 1) {
    if (t < off) red[t] += red[t + off];
    __syncthreads();
  }
  if (t == 0) o128[j] = fmaxf(red[0] + bz[j], 0.0f);
}

// ---------------- K6c: final dot ----------------
__global__ void k_final(const float* __restrict__ Wf, const float* __restrict__ bf_,
                        char* __restrict__ ws, float* __restrict__ out) {
  const int t = threadIdx.x;
  float* o128 = (float*)(ws + WS_O128);
  __shared__ float red[128];
  red[t] = o128[t] * Wf[t];
  __syncthreads();
  for (int off = 64; off >= 1; off >>= 1) {
    if (t < off) red[t] += red[t + off];
    __syncthreads();
  }
  if (t == 0) out[0] = red[0] + bf_[0];
}

extern "C" void kernel_launch(void* const* d_in, const int* in_sizes, int n_in,
                              void* d_out, int out_size, void* d_ws, size_t ws_size,
                              hipStream_t stream) {
  const float* inp   = (const float*)d_in[0];
  const float* W1    = (const float*)d_in[1];
  const float* b1    = (const float*)d_in[2];
  const float* g1    = (const float*)d_in[3];
  const float* be1   = (const float*)d_in[4];
  const float* Watt1 = (const float*)d_in[5];
  const float* batt1 = (const float*)d_in[6];
  const float* g2    = (const float*)d_in[7];
  const float* be2   = (const float*)d_in[8];
  const float* Watt2 = (const float*)d_in[9];
  const float* batt2 = (const float*)d_in[10];
  const float* Wq    = (const float*)d_in[11];
  const float* Wk    = (const float*)d_in[12];
  const float* Wv    = (const float*)d_in[13];
  const float* Wz    = (const float*)d_in[14];
  const float* bz    = (const float*)d_in[15];
  const float* Wf    = (const float*)d_in[16];
  const float* bf_   = (const float*)d_in[17];
  char* ws = (char*)d_ws;

  hipMemsetAsync(ws + WS_HIST, 0, 16384 + 64, stream);  // hist + misc
  k_main<<<dim3(1024), dim3(256), 0, stream>>>(inp, W1, b1, g1, be1, Watt1, batt1, g2, be2, Watt2, batt2, ws);
  k_reduce<<<dim3(1), dim3(256), 0, stream>>>(ws);
  k_gather<<<dim3(512), dim3(256), 0, stream>>>(ws);
  k_select<<<dim3(1), dim3(256), 0, stream>>>(ws);
  k_zs<<<dim3(64), dim3(256), 0, stream>>>(inp, W1, b1, g1, be1, Wq, Wk, Wv, ws);
  k_attn<<<dim3(1), dim3(256), 0, stream>>>(ws);
  k_wz<<<dim3(128), dim3(256), 0, stream>>>(Wz, bz, ws);
  k_final<<<dim3(1), dim3(128), 0, stream>>>(Wf, bf_, ws, (float*)d_out);
}

// Round 2
// 287.053 us; speedup vs baseline: 1.3375x; 1.3375x over previous
//
#include <hip/hip_runtime.h>

// SurvModel: x=relu(BN(in@W1+b1)); h=tanh(BN(x@Watt1+batt1)); s=h@Watt2+batt2;
// A=softmax_N(s); top64 by A desc (stable); zs=x[top]*softmax(A[top]);
// zq/zk/zv=zs@W*; zw=softmax(zq@zk^T)@zv; out=relu(zw.flat@Wz+bz)@Wf+bf.
// Split-fp32 (bf16 hi/lo, 3 MFMAs) keeps scores ~1e-6 accurate (top-64 gap ~1.3e-3).
// R2: global_load_lds staging, dbuf + counted vmcnt(8), 81920B LDS -> 2 blocks/CU.

#define NN   131072
#define DIN  768
#define DH   128
#define DA   32

using f32x4  = __attribute__((ext_vector_type(4))) float;
using bf16x8 = __attribute__((ext_vector_type(8))) __bf16;

// workspace byte offsets
#define WS_S      0            // float[131072] scores
#define WS_PZ4    524288       // float[4096] per-wave sum(exp(s))
#define WS_HIST   540672       // int[4096]
#define WS_MISC   557056       // [0]=Z f32, [2]=cnt int, [3]=bstar int
#define WS_CIDX   557120       // int[512]
#define WS_CS     559168       // float[512]
#define WS_ORDER  561216       // int[64]
#define WS_W      561472       // float[64]
#define WS_ZQ     561728       // float[2048]
#define WS_ZK     569920       // float[2048]
#define WS_ZV     578112       // float[2048]
#define WS_ZW     586304       // float[2048]
#define WS_O128   594496       // float[128]
#define WS_W1T    598016       // 24*16384 = 393216 B bf16 hi/lo transposed+preswizzled W1

__device__ __forceinline__ int s_bin(float s) {
  int b = (int)((s + 6.0f) * (4096.0f / 12.0f));
  return b < 0 ? 0 : (b > 4095 ? 4095 : b);
}

__device__ __forceinline__ void gl_lds16(const void* g, void* l) {
  __builtin_amdgcn_global_load_lds(
      (const __attribute__((address_space(1))) void*)g,
      (__attribute__((address_space(3))) void*)l, 16, 0, 0);
}

// ---------------- K0: pre-convert W1 -> bf16 hi/lo, [kc][col][8x16B units], pre-swizzled
__global__ void k_prep(const float* __restrict__ W1, char* __restrict__ ws) {
  int T = blockIdx.x * 256 + threadIdx.x;       // 0..24575
  int u = T & 7, col = (T >> 3) & 127, kc = T >> 10;
  bf16x8 ov;
  #pragma unroll
  for (int j = 0; j < 8; ++j) {
    int k = (u & 3) * 8 + j;
    float v = W1[(size_t)(kc * 32 + k) * 128 + col];
    __bf16 h = (__bf16)v;
    ov[j] = (u < 4) ? h : (__bf16)(v - (float)h);
  }
  char* dst = ws + WS_W1T + (size_t)kc * 16384 + col * 128 + ((u ^ (col & 7)) << 4);
  *(bf16x8*)dst = ov;
}

// ---------------- K1: main GEMM + h + scores ----------------
__global__ __launch_bounds__(256, 2) void k_main(
    const float* __restrict__ inp,
    const float* __restrict__ b1, const float* __restrict__ g1, const float* __restrict__ be1,
    const float* __restrict__ Watt1, const float* __restrict__ batt1,
    const float* __restrict__ g2, const float* __restrict__ be2,
    const float* __restrict__ Watt2, const float* __restrict__ batt2,
    char* __restrict__ ws)
{
  // LDS 81920B: [0,16K)A0 [16K,32K)A1 [32K,48K)B0 [48K,64K)B1  (union x-tile 64K) | [64K,80K) Watt1
  __shared__ __align__(16) char lds[81920];
  float* s_out = (float*)(ws + WS_S);
  float* pz4   = (float*)(ws + WS_PZ4);
  int*   hist  = (int*)(ws + WS_HIST);
  const char* w1t = ws + WS_W1T;

  const int t = threadIdx.x;
  const int l = t & 63;
  const int wid = t >> 6;
  const int wr = wid >> 1, wc = wid & 1;
  const int blockRow = blockIdx.x * 128;
  const float inv = 1.0f / sqrtf(1.0f + 1e-5f);

  char* Ab0 = lds;            char* Ab1 = lds + 16384;
  char* Bb0 = lds + 32768;    char* Bb1 = lds + 49152;
  float* xt  = (float*)lds;
  float* wat = (float*)(lds + 65536);

  for (int i = t; i < DH * DA; i += 256) wat[i] = Watt1[i];

  // staging addresses: thread t stages 16B units; A pre-swizzled via source address
  const int sr = t >> 3;                 // 0..31 (row offset within 32-row chunk)
  const int su = (t & 7) ^ (sr & 7);     // swizzled source unit for A
  const float* aSrc = inp + (size_t)(blockRow + sr) * DIN + su * 4;
  const char*  bSrc = w1t + t * 16;

  f32x4 acc[4][4];
  #pragma unroll
  for (int i = 0; i < 4; ++i)
    #pragma unroll
    for (int j = 0; j < 4; ++j)
      #pragma unroll
      for (int q = 0; q < 4; ++q) acc[i][j][q] = 0.0f;

#define STAGE(Abuf, Bbuf, kc_) do { \
    _Pragma("unroll") \
    for (int c = 0; c < 4; ++c) \
      gl_lds16(aSrc + (size_t)c * 24576 + (kc_) * 32, (Abuf) + c * 4096 + t * 16); \
    _Pragma("unroll") \
    for (int c = 0; c < 4; ++c) \
      gl_lds16(bSrc + (size_t)(kc_) * 16384 + c * 4096, (Bbuf) + c * 4096 + t * 16); \
  } while (0)

  STAGE(Ab0, Bb0, 0);

  const int kg = l >> 4, r15 = l & 15;
  for (int kc = 0; kc < 24; ++kc) {
    char* A = (kc & 1) ? Ab1 : Ab0;
    char* B = (kc & 1) ? Bb1 : Bb0;
    if (kc < 23) {
      char* An = (kc & 1) ? Ab0 : Ab1;
      char* Bn = (kc & 1) ? Bb0 : Bb1;
      STAGE(An, Bn, kc + 1);
      asm volatile("s_waitcnt vmcnt(8)" ::: "memory");
    } else {
      asm volatile("s_waitcnt vmcnt(0)" ::: "memory");
    }
    __builtin_amdgcn_sched_barrier(0);
    __builtin_amdgcn_s_barrier();          // this tile's DMA visible to all waves
    __builtin_amdgcn_sched_barrier(0);

    bf16x8 ahi[4], alo[4];
    #pragma unroll
    for (int mi = 0; mi < 4; ++mi) {
      int R = wr * 64 + mi * 16 + r15;
      const char* base = A + R * 128; int sw = R & 7;
      f32x4 a0 = *(const f32x4*)(base + (((kg * 2)     ^ sw) << 4));
      f32x4 a1 = *(const f32x4*)(base + (((kg * 2 + 1) ^ sw) << 4));
      #pragma unroll
      for (int j = 0; j < 4; ++j) {
        float x0 = a0[j]; __bf16 h0 = (__bf16)x0; ahi[mi][j]     = h0; alo[mi][j]     = (__bf16)(x0 - (float)h0);
        float x1 = a1[j]; __bf16 h1 = (__bf16)x1; ahi[mi][4 + j] = h1; alo[mi][4 + j] = (__bf16)(x1 - (float)h1);
      }
    }
    #pragma unroll
    for (int ni = 0; ni < 4; ++ni) {
      int C = wc * 64 + ni * 16 + r15;
      const char* cb = B + C * 128; int sw = C & 7;
      bf16x8 bhi = *(const bf16x8*)(cb + ((kg       ^ sw) << 4));
      bf16x8 blo = *(const bf16x8*)(cb + (((4 | kg) ^ sw) << 4));
      #pragma unroll
      for (int mi = 0; mi < 4; ++mi) {
        acc[mi][ni] = __builtin_amdgcn_mfma_f32_16x16x32_bf16(ahi[mi], bhi, acc[mi][ni], 0, 0, 0);
        acc[mi][ni] = __builtin_amdgcn_mfma_f32_16x16x32_bf16(ahi[mi], blo, acc[mi][ni], 0, 0, 0);
        acc[mi][ni] = __builtin_amdgcn_mfma_f32_16x16x32_bf16(alo[mi], bhi, acc[mi][ni], 0, 0, 0);
      }
    }
    __builtin_amdgcn_sched_barrier(0);
    __builtin_amdgcn_s_barrier();          // all reads of this buffer done
    __builtin_amdgcn_sched_barrier(0);
  }
#undef STAGE

  __syncthreads();
  // epilogue: BN + relu -> x tile in LDS (fp32, row-XOR-swizzled), overwrites staging
  #pragma unroll
  for (int ni = 0; ni < 4; ++ni) {
    int col = wc * 64 + ni * 16 + r15;
    float b1c = b1[col], s1c = g1[col] * inv, be1c = be1[col];
    #pragma unroll
    for (int mi = 0; mi < 4; ++mi) {
      int rbase = wr * 64 + mi * 16 + ((l >> 4) << 2);
      #pragma unroll
      for (int q = 0; q < 4; ++q) {
        int row = rbase + q;
        float xv = fmaxf((acc[mi][ni][q] + b1c) * s1c + be1c, 0.0f);
        *(float*)((char*)xt + row * 512 + ((col * 4) ^ ((row & 31) << 4))) = xv;
      }
    }
  }
  __syncthreads();
  // h = tanh(BN(x@Watt1)); s = h@Watt2 + batt2; Z partials; histogram
  {
    const int row = t >> 1, ah = t & 1;
    float hacc[16];
    #pragma unroll
    for (int a = 0; a < 16; ++a) hacc[a] = 0.0f;
    const char* xrow = (const char*)xt + row * 512;
    const int rsw = (row & 31) << 4;
    for (int cb = 0; cb < 128; cb += 4) {
      f32x4 xv = *(const f32x4*)(xrow + ((cb * 4) ^ rsw));
      #pragma unroll
      for (int u = 0; u < 4; ++u) {
        const float* wrow = wat + (cb + u) * 32 + ah * 16;
        f32x4 w0 = *(const f32x4*)(wrow);
        f32x4 w1 = *(const f32x4*)(wrow + 4);
        f32x4 w2 = *(const f32x4*)(wrow + 8);
        f32x4 w3 = *(const f32x4*)(wrow + 12);
        float xs = xv[u];
        #pragma unroll
        for (int q = 0; q < 4; ++q) {
          hacc[q]     += xs * w0[q];
          hacc[4 + q] += xs * w1[q];
          hacc[8 + q] += xs * w2[q];
          hacc[12 + q]+= xs * w3[q];
        }
      }
    }
    float partial = 0.0f;
    #pragma unroll
    for (int a = 0; a < 16; ++a) {
      int ai = ah * 16 + a;
      float hv = tanhf((hacc[a] + batt1[ai]) * (g2[ai] * inv) + be2[ai]);
      partial += hv * Watt2[ai];
    }
    partial += __shfl_xor(partial, 1, 64);
    float ev = 0.0f;
    if (ah == 0) {
      float sv = partial + batt2[0];
      s_out[blockRow + row] = sv;
      atomicAdd(&hist[s_bin(sv)], 1);
      ev = expf(sv);
    }
    #pragma unroll
    for (int off = 32; off >= 1; off >>= 1) ev += __shfl_xor(ev, off, 64);
    if (l == 0) pz4[blockIdx.x * 4 + wid] = ev;
  }
}

// ---------------- K2: Z reduce + histogram threshold ----------------
__global__ void k_reduce(char* __restrict__ ws) {
  float* pz4 = (float*)(ws + WS_PZ4);
  int* hist = (int*)(ws + WS_HIST);
  float* miscf = (float*)(ws + WS_MISC);
  int* misci = (int*)(ws + WS_MISC);
  const int t = threadIdx.x;
  __shared__ float red[256];
  __shared__ int csum[256];
  float z = 0.0f;
  for (int i = t; i < 4096; i += 256) z += pz4[i];
  red[t] = z;
  int c = 0;
  #pragma unroll
  for (int u = 0; u < 16; ++u) c += hist[t * 16 + u];
  csum[t] = c;
  __syncthreads();
  for (int off = 128; off >= 1; off >>= 1) {
    if (t < off) red[t] += red[t + off];
    __syncthreads();
  }
  if (t == 0) {
    miscf[0] = red[0];
    int cum = 0, bstar = 0;
    for (int ch = 255; ch >= 0; --ch) {
      if (cum + csum[ch] >= 64) {
        for (int b = ch * 16 + 15; b >= ch * 16; --b) {
          cum += hist[b];
          if (cum >= 64) { bstar = b; break; }
        }
        break;
      }
      cum += csum[ch];
    }
    misci[3] = bstar;
    misci[2] = 0;
  }
}

// ---------------- K3: gather candidates ----------------
__global__ void k_gather(char* __restrict__ ws) {
  const int i = blockIdx.x * 256 + threadIdx.x;
  float* s_out = (float*)(ws + WS_S);
  int* misci = (int*)(ws + WS_MISC);
  int* cidx = (int*)(ws + WS_CIDX);
  float* cs = (float*)(ws + WS_CS);
  float s = s_out[i];
  if (s_bin(s) >= misci[3]) {
    int pos = atomicAdd(&misci[2], 1);
    if (pos < 512) { cidx[pos] = i; cs[pos] = s; }
  }
}

// ---------------- K4: sort candidates, top-64 order + weights ----------------
__global__ void k_select(char* __restrict__ ws) {
  const int t = threadIdx.x;
  float* s_out = (float*)(ws + WS_S);
  int* misci = (int*)(ws + WS_MISC);
  float* miscf = (float*)(ws + WS_MISC);
  int* cidx = (int*)(ws + WS_CIDX);
  float* cs = (float*)(ws + WS_CS);
  int* order = (int*)(ws + WS_ORDER);
  float* wsel = (float*)(ws + WS_W);
  __shared__ unsigned long long keys[512];
  __shared__ float aLds[64];
  int cnt = misci[2]; if (cnt > 512) cnt = 512;
  for (int i = t; i < 512; i += 256) {
    unsigned long long kkey = 0xFFFFFFFFFFFFFFFFull;
    if (i < cnt) {
      unsigned u = __float_as_uint(cs[i]);
      u = (u & 0x80000000u) ? ~u : (u | 0x80000000u);  // ascending map
      unsigned du = ~u;                                 // descending by s
      kkey = ((unsigned long long)du << 32) | (unsigned)cidx[i];  // tie: idx asc
    }
    keys[i] = kkey;
  }
  __syncthreads();
  for (int k = 2; k <= 512; k <<= 1) {
    for (int j = k >> 1; j > 0; j >>= 1) {
      for (int i = t; i < 512; i += 256) {
        int ixj = i ^ j;
        if (ixj > i) {
          bool up = ((i & k) == 0);
          unsigned long long a = keys[i], b2 = keys[ixj];
          if (up ? (a > b2) : (a < b2)) { keys[i] = b2; keys[ixj] = a; }
        }
      }
      __syncthreads();
    }
  }
  float Z = miscf[0];
  if (t < 64) {
    int idx = (int)(keys[t] & 0xFFFFFFFFull);
    order[t] = idx;
    aLds[t] = expf(s_out[idx]) / Z;
  }
  __syncthreads();
  if (t < 64) {
    float m = aLds[0];                // sorted desc -> max
    float e = expf(aLds[t] - m);
    float sum = e;
    #pragma unroll
    for (int off = 32; off >= 1; off >>= 1) sum += __shfl_xor(sum, off, 64);
    wsel[t] = e / sum;
  }
}

// ---------------- K5: recompute x for top-64, zs, zq/zk/zv ----------------
__global__ void k_zs(const float* __restrict__ inp, const float* __restrict__ W1,
                     const float* __restrict__ b1, const float* __restrict__ g1, const float* __restrict__ be1,
                     const float* __restrict__ Wq, const float* __restrict__ Wk, const float* __restrict__ Wv,
                     char* __restrict__ ws)
{
  const int t = threadIdx.x, b = blockIdx.x;
  int* order = (int*)(ws + WS_ORDER);
  float* wsel = (float*)(ws + WS_W);
  float* zq = (float*)(ws + WS_ZQ);
  float* zk = (float*)(ws + WS_ZK);
  float* zv = (float*)(ws + WS_ZV);
  __shared__ float rowS[768];
  __shared__ float zsS[128];
  const float inv = 1.0f / sqrtf(1.0f + 1e-5f);
  int r = order[b];
  float wgt = wsel[b];
  for (int i = t; i < 768; i += 256) rowS[i] = inp[(size_t)r * 768 + i];
  __syncthreads();
  if (t < 128) {
    float d = 0.0f;
    for (int k = 0; k < 768; ++k) d += rowS[k] * W1[(size_t)k * 128 + t];
    float x = fmaxf((d + b1[t]) * (g1[t] * inv) + be1[t], 0.0f);
    zsS[t] = x * wgt;
  }
  __syncthreads();
  if (t < 96) {
    int which = t >> 5, a = t & 31;
    const float* W = (which == 0) ? Wq : ((which == 1) ? Wk : Wv);
    float d = 0.0f;
    for (int c = 0; c < 128; ++c) d += zsS[c] * W[c * 32 + a];
    float* dst = (which == 0) ? zq : ((which == 1) ? zk : zv);
    dst[b * 32 + a] = d;
  }
}

// ---------------- K6a: 64x64 attention ----------------
__global__ void k_attn(char* __restrict__ ws) {
  const int t = threadIdx.x;
  float* zq = (float*)(ws + WS_ZQ);
  float* zk = (float*)(ws + WS_ZK);
  float* zv = (float*)(ws + WS_ZV);
  float* zw = (float*)(ws + WS_ZW);
  __shared__ float q[2048], kk[2048], v[2048], P[4096];
  for (int i = t; i < 2048; i += 256) { q[i] = zq[i]; kk[i] = zk[i]; v[i] = zv[i]; }
  __syncthreads();
  for (int o = t; o < 4096; o += 256) {
    int i = o >> 6, j = o & 63;
    float d = 0.0f;
    for (int a = 0; a < 32; ++a) d += q[i * 32 + a] * kk[j * 32 + a];
    P[o] = d;
  }
  __syncthreads();
  if (t < 64) {
    float m = -1e30f;
    for (int j = 0; j < 64; ++j) m = fmaxf(m, P[t * 64 + j]);
    float sum = 0.0f;
    for (int j = 0; j < 64; ++j) { float e = expf(P[t * 64 + j] - m); P[t * 64 + j] = e; sum += e; }
    float rs = 1.0f / sum;
    for (int j = 0; j < 64; ++j) P[t * 64 + j] *= rs;
  }
  __syncthreads();
  for (int o = t; o < 2048; o += 256) {
    int i = o >> 5, a = o & 31;
    float d = 0.0f;
    for (int j = 0; j < 64; ++j) d += P[i * 64 + j] * v[j * 32 + a];
    zw[o] = d;
  }
}

// ---------------- K6b: zw.flat @ Wz + bz, relu ----------------
__global__ void k_wz(const float* __restrict__ Wz, const float* __restrict__ bz, char* __restrict__ ws) {
  const int t = threadIdx.x, j = blockIdx.x;
  float* zw = (float*)(ws + WS_ZW);
  float* o128 = (float*)(ws + WS_O128);
  __shared__ float red[256];
  float p = 0.0f;
  for (int i2 = t; i2 < 2048; i2 += 256) p += zw[i2] * Wz[(size_t)i2 * 128 + j];
  red[t] = p; __syncthreads();
  for (int off = 128; off >= 1; off >>= 1) {
    if (t < off) red[t] += red[t + off];
    __syncthreads();
  }
  if (t == 0) o128[j] = fmaxf(red[0] + bz[j], 0.0f);
}

// ---------------- K6c: final dot ----------------
__global__ void k_final(const float* __restrict__ Wf, const float* __restrict__ bf_,
                        char* __restrict__ ws, float* __restrict__ out) {
  const int t = threadIdx.x;
  float* o128 = (float*)(ws + WS_O128);
  __shared__ float red[128];
  red[t] = o128[t] * Wf[t];
  __syncthreads();
  for (int off = 64; off >= 1; off >>= 1) {
    if (t < off) red[t] += red[t + off];
    __syncthreads();
  }
  if (t == 0) out[0] = red[0] + bf_[0];
}

extern "C" void kernel_launch(void* const* d_in, const int* in_sizes, int n_in,
                              void* d_out, int out_size, void* d_ws, size_t ws_size,
                              hipStream_t stream) {
  const float* inp   = (const float*)d_in[0];
  const float* W1    = (const float*)d_in[1];
  const float* b1    = (const float*)d_in[2];
  const float* g1    = (const float*)d_in[3];
  const float* be1   = (const float*)d_in[4];
  const float* Watt1 = (const float*)d_in[5];
  const float* batt1 = (const float*)d_in[6];
  const float* g2    = (const float*)d_in[7];
  const float* be2   = (const float*)d_in[8];
  const float* Watt2 = (const float*)d_in[9];
  const float* batt2 = (const float*)d_in[10];
  const float* Wq    = (const float*)d_in[11];
  const float* Wk    = (const float*)d_in[12];
  const float* Wv    = (const float*)d_in[13];
  const float* Wz    = (const float*)d_in[14];
  const float* bz    = (const float*)d_in[15];
  const float* Wf    = (const float*)d_in[16];
  const float* bf_   = (const float*)d_in[17];
  char* ws = (char*)d_ws;

  hipMemsetAsync(ws + WS_HIST, 0, 16384 + 64, stream);  // hist + misc
  k_prep<<<dim3(96), dim3(256), 0, stream>>>(W1, ws);
  k_main<<<dim3(1024), dim3(256), 0, stream>>>(inp, b1, g1, be1, Watt1, batt1, g2, be2, Watt2, batt2, ws);
  k_reduce<<<dim3(1), dim3(256), 0, stream>>>(ws);
  k_gather<<<dim3(512), dim3(256), 0, stream>>>(ws);
  k_select<<<dim3(1), dim3(256), 0, stream>>>(ws);
  k_zs<<<dim3(64), dim3(256), 0, stream>>>(inp, W1, b1, g1, be1, Wq, Wk, Wv, ws);
  k_attn<<<dim3(1), dim3(256), 0, stream>>>(ws);
  k_wz<<<dim3(128), dim3(256), 0, stream>>>(Wz, bz, ws);
  k_final<<<dim3(1), dim3(128), 0, stream>>>(Wf, bf_, ws, (float*)d_out);
}